// Round 8
// baseline (1438.680 us; speedup 1.0000x reference)
//
#include <hip/hip_runtime.h>
#include <stdint.h>

#define H 512
#define KAUG 528
#define KT_N 33            // K tiles of 16 (528/16)
#define LROW 536           // LDS row stride in shorts (16B aligned)
#define NROW 32
#define WMAT_ELEMS (16 * KT_N * 4 * 512)   // 16 ntL * 33 kt * 4 gates * 512 = 1,081,344
#define NTL_ELEMS  (KT_N * 4 * 512)        // 67,584 shorts per ntL slice
#define RING_W 3072                        // 3 slots x 1024 shorts per wave
#define T_DEC 32
#define B_TOT 4096

typedef __attribute__((ext_vector_type(8))) short short8;
typedef __attribute__((ext_vector_type(16))) float floatx16;

typedef __attribute__((address_space(1))) const void* gas_p;
typedef __attribute__((address_space(3))) void* las_p;

__device__ __forceinline__ unsigned short f2bf(float x) {
  union { float f; unsigned int u; } v; v.f = x;
  unsigned int u = v.u;
  return (unsigned short)((u + 0x7FFFu + ((u >> 16) & 1u)) >> 16);
}
__device__ __forceinline__ float bf2f(unsigned short s) {
  union { unsigned int u; float f; } v; v.u = ((unsigned int)s) << 16;
  return v.f;
}
__device__ __forceinline__ float rcpf(float x) { return __builtin_amdgcn_rcpf(x); }
__device__ __forceinline__ float sigm(float x) { return rcpf(1.0f + __expf(-x)); }
__device__ __forceinline__ float tanh_f(float x) {
  return 1.0f - 2.0f * rcpf(1.0f + __expf(2.0f * x));
}

#define MFMA(A, B, C) __builtin_amdgcn_mfma_f32_32x32x16_bf16(A, B, C, 0, 0, 0)

// Stage one gate-pair (2 x 512 shorts) into a wave-private ring slot, async.
// src already includes this lane's +lane*8 offset; dst is wave-uniform.
__device__ __forceinline__ void stage_half(const short* src, short* dst) {
  __builtin_amdgcn_global_load_lds((gas_p)(src),       (las_p)(dst),       16, 0, 0);
  __builtin_amdgcn_global_load_lds((gas_p)(src + 512), (las_p)(dst + 512), 16, 0, 0);
}

// ---------------- prep: build augmented tile-packed bf16 weights (R1) --------
// W_aug[n][ka]: ka<512 -> Wh[n][ka]; 512..515 -> Wi[n][ka-512]; 516 -> b[n]; else 0
//   idx = ((ntL*33 + kt)*4 + g)*512 + lanep*8 + ks
__global__ void prep_weights(
    const float* __restrict__ Wh_s, const float* __restrict__ Wi_s, const float* __restrict__ b_s,
    const float* __restrict__ Wh_p, const float* __restrict__ Wi_p, const float* __restrict__ b_p,
    const float* __restrict__ Wh_d, const float* __restrict__ Wi_d, const float* __restrict__ b_d,
    const float* __restrict__ Wh_i, const float* __restrict__ Wi_i, const float* __restrict__ b_i,
    short* __restrict__ wpack)
{
  int idx = blockIdx.x * 256 + threadIdx.x;
  const int per = 2048 * KAUG;
  if (idx >= 4 * per) return;
  int mat = idx / per;
  int rem = idx - mat * per;
  int n = rem / KAUG;
  int ka = rem - n * KAUG;
  const float* Wh; const float* Wi; const float* bb;
  if (mat == 0)      { Wh = Wh_s; Wi = Wi_s; bb = b_s; }
  else if (mat == 1) { Wh = Wh_p; Wi = Wi_p; bb = b_p; }
  else if (mat == 2) { Wh = Wh_d; Wi = Wi_d; bb = b_d; }
  else               { Wh = Wh_i; Wi = Wi_i; bb = b_i; }
  float v;
  if (ka < 512)      v = Wh[n * 512 + ka];
  else if (ka < 516) v = Wi[n * 4 + (ka - 512)];
  else if (ka == 516) v = bb[n];
  else               v = 0.0f;
  int g = n >> 9, ntL = (n >> 5) & 15, ni = n & 31;
  int kt = ka >> 4, kh = (ka >> 3) & 1, ks = ka & 7;
  int lanep = kh * 32 + ni;
  wpack[(size_t)mat * WMAT_ELEMS +
        (((((size_t)ntL * KT_N + kt) * 4 + g) << 9) + (lanep << 3) + ks)] = (short)f2bf(v);
}

// ---------------- staged gate matmul: kt0..31, SB, kt32 ----------------------
// Wave-private 3-slot LDS ring; half-kt h lives in slot h%3 (66 halves = 0 mod 3
// so the mapping is continuous across steps). Each kt: stage next (i,f), wait
// vmcnt(4), consume (i,f); stage next (g,o) into the just-freed slot, wait,
// consume (g,o). Loads stay 1 kt (~190cy of compute) ahead of use; never drain.
// The SB before kt32 also publishes the aug-col writes (x feedback) of the
// previous phase. Caller must have staged halves 0,1 (prologue) with p=0.
__device__ __forceinline__ void lstm_gates_staged(
    const short* aptr, const short* wmn_lane, short* slots, int lane, int& p,
    floatx16& ai, floatx16& af, floatx16& ag, floatx16& ao)
{
  #pragma unroll 1
  for (int kt = 0; kt < 32; ++kt) {
    int ps = p + 2; if (ps >= 3) ps -= 3;
    stage_half(wmn_lane + (2 * kt + 2) * 1024, slots + ps * 1024);   // (i,f) of kt+1
    asm volatile("s_waitcnt vmcnt(4)" ::: "memory");
    short8 a  = *(const short8*)(aptr + kt * 16);
    short8 b0 = *(const short8*)(slots + p * 1024 + (lane << 3));
    short8 b1 = *(const short8*)(slots + p * 1024 + 512 + (lane << 3));
    ai = MFMA(a, b0, ai); af = MFMA(a, b1, af);
    stage_half(wmn_lane + (2 * kt + 3) * 1024, slots + p * 1024);    // (g,o) of kt+1
    asm volatile("s_waitcnt vmcnt(4)" ::: "memory");
    int p1 = p + 1; if (p1 >= 3) p1 -= 3;
    short8 b2 = *(const short8*)(slots + p1 * 1024 + (lane << 3));
    short8 b3 = *(const short8*)(slots + p1 * 1024 + 512 + (lane << 3));
    ag = MFMA(a, b2, ag); ao = MFMA(a, b3, ao);
    p = ps;
  }
  __syncthreads();   // SB: h-col reads done block-wide; aug writes visible
  { // kt = 32 (aug: x cols + bias); stage next STEP's halves 0,1 (same data)
    int ps = p + 2; if (ps >= 3) ps -= 3;
    stage_half(wmn_lane, slots + ps * 1024);                         // half 0'
    asm volatile("s_waitcnt vmcnt(4)" ::: "memory");
    short8 a  = *(const short8*)(aptr + 512);
    short8 b0 = *(const short8*)(slots + p * 1024 + (lane << 3));
    short8 b1 = *(const short8*)(slots + p * 1024 + 512 + (lane << 3));
    ai = MFMA(a, b0, ai); af = MFMA(a, b1, af);
    stage_half(wmn_lane + 1024, slots + p * 1024);                   // half 1'
    asm volatile("s_waitcnt vmcnt(4)" ::: "memory");
    int p1 = p + 1; if (p1 >= 3) p1 -= 3;
    short8 b2 = *(const short8*)(slots + p1 * 1024 + (lane << 3));
    short8 b3 = *(const short8*)(slots + p1 * 1024 + 512 + (lane << 3));
    ag = MFMA(a, b2, ag); ao = MFMA(a, b3, ao);
    p = ps;
  }
}

__device__ __forceinline__ void write_h16(short* hl, int lane, int wv, const float hnew[16]) {
  int arow = lane & 31, ahalf = lane >> 5;
  int col = (wv << 5) + arow;
  #pragma unroll
  for (int r = 0; r < 16; ++r) {
    int row = (r & 3) + ((r >> 2) << 3) + (ahalf << 2);
    hl[row * LROW + col] = (short)f2bf(hnew[r]);
  }
}

// ---------------- encoder: single hl, staged weights, 2 barriers/step --------
__global__ __launch_bounds__(1024) void lstm_encoder(
    const float* __restrict__ speed, const float* __restrict__ pos,
    const short* __restrict__ wpack,
    short* __restrict__ h_enc, float* __restrict__ c_enc)
{
  __shared__ short hl[NROW * LROW];      // 34,304 B
  __shared__ short ring[16 * RING_W];    // 98,304 B  (total 132,608 B)
  int tid = threadIdx.x;
  int b = blockIdx.x;
  int xcd = b & 7, slot = b >> 3;
  int enc = xcd >> 2;               // XCDs 0-3: speed, 4-7: pos (L2 locality)
  int rg = slot * 4 + (xcd & 3);    // 0..127
  int r0 = rg * 32;
  const float* xin = enc ? pos : speed;
  const short* wm = wpack + (size_t)enc * WMAT_ELEMS;
  int lane = tid & 63, wv = tid >> 6;   // wv in [0,16)
  int arow = lane & 31, ahalf = lane >> 5;

  const short* wmn_lane = wm + (size_t)wv * NTL_ELEMS + (lane << 3);
  short* slots = ring + wv * RING_W;
  // prologue: stage halves 0,1 -> slots 0,1 (async; covered by init below)
  stage_half(wmn_lane, slots);
  stage_half(wmn_lane + 1024, slots + 1024);
  int p = 0;

  for (int i = tid; i < NROW * LROW; i += 1024) hl[i] = 0;
  __syncthreads();
  if (tid < 32) hl[tid * LROW + 516] = (short)0x3F80;   // bias lane = 1.0
  if (tid < 128) {
    int r = tid >> 2, c = tid & 3;
    hl[r * LROW + 512 + c] = (short)f2bf(xin[(r0 + r) * 64 + c]);   // x_0
  }
  __syncthreads();

  float c_reg[16];
  #pragma unroll
  for (int r = 0; r < 16; ++r) c_reg[r] = 0.0f;
  float hnew[16];
  const short* aptr = hl + arow * LROW + ahalf * 8;

  for (int t = 0; t < 16; ++t) {
    floatx16 ai = (floatx16)0.0f, af = (floatx16)0.0f,
             ag = (floatx16)0.0f, ao = (floatx16)0.0f;
    lstm_gates_staged(aptr, wmn_lane, slots, lane, p, ai, af, ag, ao);
    #pragma unroll
    for (int r = 0; r < 16; ++r) {
      float si = sigm(ai[r]);
      float sf = sigm(af[r]);
      float tg = tanh_f(ag[r]);
      float so = sigm(ao[r]);
      float cn = sf * c_reg[r] + si * tg;
      c_reg[r] = cn;
      hnew[r] = so * tanh_f(cn);
    }
    write_h16(hl, lane, wv, hnew);          // safe: SB inside gates ended reads
    __syncthreads();                        // SA: h(t+1) complete
    if (t < 15 && tid < 128) {              // x(t+1) into aug; published by next SB
      int r = tid >> 2, c = tid & 3;
      hl[r * LROW + 512 + c] = (short)f2bf(xin[(r0 + r) * 64 + (t + 1) * 4 + c]);
    }
  }

  for (int i = tid; i < 32 * 512; i += 1024) {
    int r = i >> 9, k = i & 511;
    h_enc[((size_t)(enc * B_TOT + r0 + r) << 9) + k] = hl[r * LROW + k];
  }
  int col = (wv << 5) + arow;
  #pragma unroll
  for (int r = 0; r < 16; ++r) {
    int row = (r & 3) + ((r >> 2) << 3) + (ahalf << 2);
    c_enc[((size_t)(enc * B_TOT + r0 + row) << 9) + col] = c_reg[r];
  }
}

// ---------------- decoder: single hl, staged weights, heads after SA ---------
__global__ __launch_bounds__(1024) void lstm_decoder(
    const float* __restrict__ speed, const float* __restrict__ pos,
    const short* __restrict__ wpack,
    const short* __restrict__ h_enc, const float* __restrict__ c_enc,
    const float* __restrict__ W_fs, const float* __restrict__ b_fs,
    const float* __restrict__ W_fc, const float* __restrict__ b_fc,
    const float* __restrict__ W_emb, const float* __restrict__ b_emb,
    float* __restrict__ out)
{
  __shared__ short hl[NROW * LROW];      // 34,304 B
  __shared__ short ring[16 * RING_W];    // 98,304 B
  int tid = threadIdx.x;
  int b = blockIdx.x;
  int xcd = b & 7, slot = b >> 3;
  int chain = xcd >> 2;
  int rg = slot * 4 + (xcd & 3);
  int r0 = rg * 32;
  const short* wm = wpack + (size_t)(2 + chain) * WMAT_ELEMS;
  int lane = tid & 63, wv = tid >> 6;   // wv in [0,16)
  int arow = lane & 31, ahalf = lane >> 5;

  const short* wmn_lane = wm + (size_t)wv * NTL_ELEMS + (lane << 3);
  short* slots = ring + wv * RING_W;
  stage_half(wmn_lane, slots);           // prologue halves 0,1
  stage_half(wmn_lane + 1024, slots + 1024);
  int p = 0;

  for (int i = tid; i < NROW * LROW; i += 1024) hl[i] = 0;
  __syncthreads();
  for (int i = tid; i < 32 * 512; i += 1024) {
    int r = i >> 9, k = i & 511;
    float h0 = bf2f((unsigned short)h_enc[((size_t)(r0 + r) << 9) + k])
             + bf2f((unsigned short)h_enc[((size_t)(B_TOT + r0 + r) << 9) + k]);
    hl[r * LROW + k] = (short)f2bf(h0);
  }
  if (tid < 32) hl[tid * LROW + 516] = (short)0x3F80;
  {
    const float* last = chain ? pos : speed;
    if (tid < 128) {
      int r = tid >> 2, c = tid & 3;
      hl[r * LROW + 512 + c] = (short)f2bf(last[(r0 + r) * 64 + 60 + c]); // x(0)
    }
  }

  float c_reg[16];
  {
    int col = (wv << 5) + arow;
    #pragma unroll
    for (int r = 0; r < 16; ++r) {
      int row = (r & 3) + ((r >> 2) << 3) + (ahalf << 2);
      size_t gi = ((size_t)(r0 + row) << 9) + col;
      c_reg[r] = c_enc[gi] + c_enc[gi + (((size_t)B_TOT) << 9)];
    }
  }
  __syncthreads();

  const short* aptr = hl + arow * LROW + ahalf * 8;
  float hnew[16];
  for (int t = 0; t < T_DEC; ++t) {
    floatx16 ai = (floatx16)0.0f, af = (floatx16)0.0f,
             ag = (floatx16)0.0f, ao = (floatx16)0.0f;
    lstm_gates_staged(aptr, wmn_lane, slots, lane, p, ai, af, ag, ao);

    #pragma unroll
    for (int r = 0; r < 16; ++r) {
      float si = sigm(ai[r]);
      float sf = sigm(af[r]);
      float tg = tanh_f(ag[r]);
      float so = sigm(ao[r]);
      float cn = sf * c_reg[r] + si * tg;
      c_reg[r] = cn;
      hnew[r] = so * tanh_f(cn);
    }
    write_h16(hl, lane, wv, hnew);          // safe: SB inside gates ended reads
    __syncthreads();                        // SA: h(t+1) complete

    // heads: wave wv -> rows [wv*2, wv*2+2); no trailing barrier (next SB orders
    // the aug x-writes). Head weights from global (L1-resident).
    #pragma unroll 1
    for (int r = 0; r < 2; ++r) {
      int row = wv * 2 + r;
      const short8 hvs = *(const short8*)(hl + row * LROW + lane * 8);
      float hv[8];
      #pragma unroll
      for (int j = 0; j < 8; ++j) hv[j] = bf2f((unsigned short)hvs[j]);
      if (chain == 0) {
        float p0 = 0.f, p1 = 0.f, p2 = 0.f, p3 = 0.f;
        #pragma unroll
        for (int j = 0; j < 8; ++j) {
          p0 += hv[j] * W_fs[0 * 512 + lane * 8 + j];
          p1 += hv[j] * W_fs[1 * 512 + lane * 8 + j];
          p2 += hv[j] * W_fs[2 * 512 + lane * 8 + j];
          p3 += hv[j] * W_fs[3 * 512 + lane * 8 + j];
        }
        #pragma unroll
        for (int off = 32; off > 0; off >>= 1) {
          p0 += __shfl_xor(p0, off);
          p1 += __shfl_xor(p1, off);
          p2 += __shfl_xor(p2, off);
          p3 += __shfl_xor(p3, off);
        }
        float s0 = fminf(fmaxf(p0 + b_fs[0], -100.0f), 100.0f);
        float s1 = fminf(fmaxf(p1 + b_fs[1], -100.0f), 100.0f);
        float s2 = fminf(fmaxf(p2 + b_fs[2], -100.0f), 100.0f);
        float s3 = fminf(fmaxf(p3 + b_fs[3], -100.0f), 100.0f);
        if (lane < 4) {
          float v = (lane == 0) ? s0 : (lane == 1) ? s1 : (lane == 2) ? s2 : s3;
          out[(size_t)(r0 + row) * 128 + t * 4 + lane] = v;       // speed_outputs
          hl[row * LROW + 512 + lane] = (short)f2bf(v);           // x(t+1) feedback
        }
      } else {
        float p0 = 0.f, p1 = 0.f;
        #pragma unroll
        for (int j = 0; j < 8; ++j) {
          p0 += hv[j] * W_fc[0 * 512 + lane * 8 + j];
          p1 += hv[j] * W_fc[1 * 512 + lane * 8 + j];
        }
        #pragma unroll
        for (int off = 32; off > 0; off >>= 1) {
          p0 += __shfl_xor(p0, off);
          p1 += __shfl_xor(p1, off);
        }
        float it0 = fmaxf(p0 + b_fc[0], 0.0f);
        float it1 = fmaxf(p1 + b_fc[1], 0.0f);
        if (lane < 4) {
          float lp = fmaxf(W_emb[lane * 2] * it0 + W_emb[lane * 2 + 1] * it1 + b_emb[lane], 0.0f);
          hl[row * LROW + 512 + lane] = (short)f2bf(lp);          // x(t+1) feedback
        }
        if (t == T_DEC - 1 && lane < 2) {
          float m = fmaxf(it0, it1);
          float e0 = __expf(it0 - m), e1 = __expf(it1 - m);
          float v = ((lane == 0) ? e0 : e1) * rcpf(e0 + e1);
          out[(size_t)524288 + (size_t)(r0 + row) * 2 + lane] = v; // crossing
        }
      }
    }
  }
}

extern "C" void kernel_launch(void* const* d_in, const int* in_sizes, int n_in,
                              void* d_out, int out_size, void* d_ws, size_t ws_size,
                              hipStream_t stream)
{
  const float* speed    = (const float*)d_in[0];
  const float* pos      = (const float*)d_in[1];
  const float* enc_s_Wi = (const float*)d_in[2];
  const float* enc_s_Wh = (const float*)d_in[3];
  const float* enc_s_b  = (const float*)d_in[4];
  const float* enc_p_Wi = (const float*)d_in[5];
  const float* enc_p_Wh = (const float*)d_in[6];
  const float* enc_p_b  = (const float*)d_in[7];
  const float* dec_s_Wi = (const float*)d_in[8];
  const float* dec_s_Wh = (const float*)d_in[9];
  const float* dec_s_b  = (const float*)d_in[10];
  const float* dec_i_Wi = (const float*)d_in[11];
  const float* dec_i_Wh = (const float*)d_in[12];
  const float* dec_i_b  = (const float*)d_in[13];
  const float* W_fs     = (const float*)d_in[14];
  const float* b_fs     = (const float*)d_in[15];
  const float* W_fc     = (const float*)d_in[16];
  const float* b_fc     = (const float*)d_in[17];
  const float* W_emb    = (const float*)d_in[18];
  const float* b_emb    = (const float*)d_in[19];
  float* out = (float*)d_out;

  char* ws = (char*)d_ws;
  short* wpack = (short*)ws;                 // 4 x 2,162,688 B = 8,650,752 B
  short* h_enc = (short*)(ws + 8650752);     // 2 x 4096 x 512 bf16 = 8,388,608 B
  float* c_enc = (float*)(ws + 17039360);    // 2 x 4096 x 512 f32  = 16,777,216 B

  prep_weights<<<16896, 256, 0, stream>>>(
      enc_s_Wh, enc_s_Wi, enc_s_b,
      enc_p_Wh, enc_p_Wi, enc_p_b,
      dec_s_Wh, dec_s_Wi, dec_s_b,
      dec_i_Wh, dec_i_Wi, dec_i_b,
      wpack);
  lstm_encoder<<<256, 1024, 0, stream>>>(speed, pos, wpack, h_enc, c_enc);
  lstm_decoder<<<256, 1024, 0, stream>>>(speed, pos, wpack, h_enc, c_enc,
                                         W_fs, b_fs, W_fc, b_fc, W_emb, b_emb, out);
}

// Round 9
// 1353.278 us; speedup vs baseline: 1.0631x; 1.0631x over previous
//
#include <hip/hip_runtime.h>
#include <stdint.h>

#define H 512
#define KAUG 528
#define KT_N 33            // K tiles of 16 (528/16)
#define LROW 536           // LDS row stride in shorts (16B aligned, 2-way bank alias = free)
#define NROW 32
#define WMAT_ELEMS (16 * KT_N * 4 * 512)   // 16 ntL * 33 kt * 4 gates * 512 = 1,081,344
#define T_DEC 32
#define B_TOT 4096

typedef __attribute__((ext_vector_type(8))) short short8;
typedef __attribute__((ext_vector_type(16))) float floatx16;

__device__ __forceinline__ unsigned short f2bf(float x) {
  union { float f; unsigned int u; } v; v.f = x;
  unsigned int u = v.u;
  return (unsigned short)((u + 0x7FFFu + ((u >> 16) & 1u)) >> 16);
}
__device__ __forceinline__ float bf2f(unsigned short s) {
  union { unsigned int u; float f; } v; v.u = ((unsigned int)s) << 16;
  return v.f;
}
__device__ __forceinline__ float rcpf(float x) { return __builtin_amdgcn_rcpf(x); }
__device__ __forceinline__ float sigm(float x) { return rcpf(1.0f + __expf(-x)); }
__device__ __forceinline__ float tanh_f(float x) {
  return 1.0f - 2.0f * rcpf(1.0f + __expf(2.0f * x));
}

#define MFMA(A, B, C) __builtin_amdgcn_mfma_f32_32x32x16_bf16(A, B, C, 0, 0, 0)

// ---------------- prep: build augmented tile-packed bf16 weights (R1) --------
// W_aug[n][ka]: ka<512 -> Wh[n][ka]; 512..515 -> Wi[n][ka-512]; 516 -> b[n]; else 0
//   idx = ((ntL*33 + kt)*4 + g)*512 + lanep*8 + ks
__global__ void prep_weights(
    const float* __restrict__ Wh_s, const float* __restrict__ Wi_s, const float* __restrict__ b_s,
    const float* __restrict__ Wh_p, const float* __restrict__ Wi_p, const float* __restrict__ b_p,
    const float* __restrict__ Wh_d, const float* __restrict__ Wi_d, const float* __restrict__ b_d,
    const float* __restrict__ Wh_i, const float* __restrict__ Wi_i, const float* __restrict__ b_i,
    short* __restrict__ wpack)
{
  int idx = blockIdx.x * 256 + threadIdx.x;
  const int per = 2048 * KAUG;
  if (idx >= 4 * per) return;
  int mat = idx / per;
  int rem = idx - mat * per;
  int n = rem / KAUG;
  int ka = rem - n * KAUG;
  const float* Wh; const float* Wi; const float* bb;
  if (mat == 0)      { Wh = Wh_s; Wi = Wi_s; bb = b_s; }
  else if (mat == 1) { Wh = Wh_p; Wi = Wi_p; bb = b_p; }
  else if (mat == 2) { Wh = Wh_d; Wi = Wi_d; bb = b_d; }
  else               { Wh = Wh_i; Wi = Wi_i; bb = b_i; }
  float v;
  if (ka < 512)      v = Wh[n * 512 + ka];
  else if (ka < 516) v = Wi[n * 4 + (ka - 512)];
  else if (ka == 516) v = bb[n];
  else               v = 0.0f;
  int g = n >> 9, ntL = (n >> 5) & 15, ni = n & 31;
  int kt = ka >> 4, kh = (ka >> 3) & 1, ks = ka & 7;
  int lanep = kh * 32 + ni;
  wpack[(size_t)mat * WMAT_ELEMS +
        (((((size_t)ntL * KT_N + kt) * 4 + g) << 9) + (lanep << 3) + ks)] = (short)f2bf(v);
}

// ---------------- encoder LSTM step (R1 version: 16 waves, 33 kt) ------------
__device__ __forceinline__ void lstm_step_mfma(
    const short* hl, const short* __restrict__ wm,
    int lane, int wv, float c_reg[16], float hnew[16])
{
  int arow = lane & 31, ahalf = lane >> 5;
  const short* aptr = hl + arow * LROW + ahalf * 8;
  const short* bp = wm + (size_t)wv * (KT_N * 4 * 512) + (lane << 3);
  floatx16 ai = (floatx16)0.0f, af = (floatx16)0.0f, ag = (floatx16)0.0f, ao = (floatx16)0.0f;
  #pragma unroll 3
  for (int kt = 0; kt < KT_N; ++kt) {
    short8 a  = *(const short8*)(aptr + kt * 16);
    short8 b0 = *(const short8*)(bp);
    short8 b1 = *(const short8*)(bp + 512);
    short8 b2 = *(const short8*)(bp + 1024);
    short8 b3 = *(const short8*)(bp + 1536);
    bp += 2048;
    ai = MFMA(a, b0, ai); af = MFMA(a, b1, af);
    ag = MFMA(a, b2, ag); ao = MFMA(a, b3, ao);
  }
  #pragma unroll
  for (int r = 0; r < 16; ++r) {
    float si = sigm(ai[r]);
    float sf = sigm(af[r]);
    float tg = tanh_f(ag[r]);
    float so = sigm(ao[r]);
    float cn = sf * c_reg[r] + si * tg;
    c_reg[r] = cn;
    hnew[r] = so * tanh_f(cn);
  }
}

__device__ __forceinline__ void write_h16(short* hl, int lane, int wv, const float hnew[16]) {
  int arow = lane & 31, ahalf = lane >> 5;
  int col = (wv << 5) + arow;
  #pragma unroll
  for (int r = 0; r < 16; ++r) {
    int row = (r & 3) + ((r >> 2) << 3) + (ahalf << 2);
    hl[row * LROW + col] = (short)f2bf(hnew[r]);
  }
}

// ---------------- encoder: dbuf h -> ONE barrier per step (R6, known-good) ---
__global__ __launch_bounds__(1024) void lstm_encoder(
    const float* __restrict__ speed, const float* __restrict__ pos,
    const short* __restrict__ wpack,
    short* __restrict__ h_enc, float* __restrict__ c_enc)
{
  __shared__ short hl[2][NROW * LROW];
  int tid = threadIdx.x;
  int b = blockIdx.x;
  int xcd = b & 7, slot = b >> 3;
  int enc = xcd >> 2;               // XCDs 0-3: speed, 4-7: pos (L2 locality)
  int rg = slot * 4 + (xcd & 3);    // 0..127
  int r0 = rg * 32;
  const float* xin = enc ? pos : speed;
  const short* wm = wpack + (size_t)enc * WMAT_ELEMS;

  {
    short* hz = &hl[0][0];
    for (int i = tid; i < 2 * NROW * LROW; i += 1024) hz[i] = 0;
  }
  __syncthreads();
  if (tid < 64) hl[tid >> 5][(tid & 31) * LROW + 516] = (short)0x3F80;  // bias, both bufs
  if (tid < 128) {
    int r = tid >> 2, c = tid & 3;
    hl[0][r * LROW + 512 + c] = (short)f2bf(xin[(r0 + r) * 64 + c]);    // x_0
  }
  __syncthreads();

  int lane = tid & 63, wv = tid >> 6;   // wv in [0,16)
  float c_reg[16];
  #pragma unroll
  for (int r = 0; r < 16; ++r) c_reg[r] = 0.0f;
  float hnew[16];

  for (int t = 0; t < 16; ++t) {
    const short* cb = hl[t & 1];
    short* nb = &hl[(t + 1) & 1][0];
    lstm_step_mfma(cb, wm, lane, wv, c_reg, hnew);
    write_h16(nb, lane, wv, hnew);
    if (t < 15 && tid < 128) {
      int r = tid >> 2, c = tid & 3;
      nb[r * LROW + 512 + c] = (short)f2bf(xin[(r0 + r) * 64 + (t + 1) * 4 + c]);
    }
    __syncthreads();
  }

  // final h lives in hl[0] (t=15 wrote buf (15+1)&1 = 0)
  for (int i = tid; i < 32 * 512; i += 1024) {
    int r = i >> 9, k = i & 511;
    h_enc[((size_t)(enc * B_TOT + r0 + r) << 9) + k] = hl[0][r * LROW + k];
  }
  int arow = lane & 31, ahalf = lane >> 5;
  int col = (wv << 5) + arow;
  #pragma unroll
  for (int r = 0; r < 16; ++r) {
    int row = (r & 3) + ((r >> 2) << 3) + (ahalf << 2);
    c_enc[((size_t)(enc * B_TOT + r0 + row) << 9) + col] = c_reg[r];
  }
}

// ---------------- decoder: 512 thr, dbuf h, x-direct act, depth-2 prefetch ---
// 8 waves: wave wv owns h-cols [wv*64, wv*64+64) (jt=0,1). k-loop runs kt 0..31
// (Wh·h); Wi·x + b added in f32 during activation (register Wx/b, f32 x in LDS).
// The 4 gate B-fragments are register-prefetched one full kt ahead (depth-2
// rolling buffer, 32 VGPRs) so L2 latency overlaps the MFMA pipe. At 512
// threads the VGPR budget is 256/thread -> no spill (R3's failure mode was the
// 128-cap at 1024 threads).
// Two barriers/step: [k-loop+act+write_h(nb)] B1 [heads(nb) -> out + x] B2.
__global__ __launch_bounds__(512) void lstm_decoder(
    const float* __restrict__ speed, const float* __restrict__ pos,
    const short* __restrict__ wpack,
    const float* __restrict__ dWi_s, const float* __restrict__ db_s,
    const float* __restrict__ dWi_i, const float* __restrict__ db_i,
    const short* __restrict__ h_enc, const float* __restrict__ c_enc,
    const float* __restrict__ W_fs, const float* __restrict__ b_fs,
    const float* __restrict__ W_fc, const float* __restrict__ b_fc,
    const float* __restrict__ W_emb, const float* __restrict__ b_emb,
    float* __restrict__ out)
{
  __shared__ short hl[2][NROW * LROW];
  __shared__ float xs[2][32][4];
  int tid = threadIdx.x;
  int b = blockIdx.x;
  int xcd = b & 7, slot = b >> 3;
  int chain = xcd >> 2;
  int rg = slot * 4 + (xcd & 3);
  int r0 = rg * 32;
  const short* wm = wpack + (size_t)(2 + chain) * WMAT_ELEMS;
  int lane = tid & 63, wv = tid >> 6;          // wv in [0,8)
  int arow = lane & 31, ahalf = lane >> 5;

  // init hl[0] = h_se + h_pe (cols 0..511; cols 512+ never read in decoder)
  for (int i = tid; i < 32 * 512; i += 512) {
    int r = i >> 9, k = i & 511;
    float h0 = bf2f((unsigned short)h_enc[((size_t)(r0 + r) << 9) + k])
             + bf2f((unsigned short)h_enc[((size_t)(B_TOT + r0 + r) << 9) + k]);
    hl[0][r * LROW + k] = (short)f2bf(h0);
  }
  // x(0) = last input frame, f32
  {
    const float* last = chain ? pos : speed;
    if (tid < 128) {
      int r = tid >> 2, c = tid & 3;
      xs[0][r][c] = last[(r0 + r) * 64 + 60 + c];
    }
  }

  // c init (D-layout)
  float c_reg[2][16];
  #pragma unroll
  for (int jt = 0; jt < 2; ++jt) {
    int col = wv * 64 + jt * 32 + arow;
    #pragma unroll
    for (int r = 0; r < 16; ++r) {
      int row = (r & 3) + ((r >> 2) << 3) + (ahalf << 2);
      size_t gi = ((size_t)(r0 + row) << 9) + col;
      c_reg[jt][r] = c_enc[gi] + c_enc[gi + (((size_t)B_TOT) << 9)];
    }
  }

  // per-thread Wx/b for this thread's two output columns (loaded once)
  const float* dWi = chain ? dWi_i : dWi_s;
  const float* dbv = chain ? db_i  : db_s;
  float wx[2][4][4], wb[2][4];
  #pragma unroll
  for (int jt = 0; jt < 2; ++jt) {
    int col = wv * 64 + jt * 32 + arow;
    #pragma unroll
    for (int g = 0; g < 4; ++g) {
      int n = g * 512 + col;
      #pragma unroll
      for (int c = 0; c < 4; ++c) wx[jt][g][c] = dWi[n * 4 + c];
      wb[jt][g] = dbv[n];
    }
  }

  // head weights in registers (R0/R6-proven at 512 threads)
  float wro[4][8], hb[4], we[8], be[4];
  if (chain == 0) {
    #pragma unroll
    for (int o = 0; o < 4; ++o) {
      #pragma unroll
      for (int j = 0; j < 8; ++j) wro[o][j] = W_fs[o * 512 + lane * 8 + j];
      hb[o] = b_fs[o];
    }
  } else {
    #pragma unroll
    for (int o = 0; o < 2; ++o) {
      #pragma unroll
      for (int j = 0; j < 8; ++j) wro[o][j] = W_fc[o * 512 + lane * 8 + j];
      hb[o] = b_fc[o];
    }
    #pragma unroll
    for (int j = 0; j < 8; ++j) we[j] = W_emb[j];
    #pragma unroll
    for (int o = 0; o < 4; ++o) be[o] = b_emb[o];
  }
  __syncthreads();

  for (int t = 0; t < T_DEC; ++t) {
    const short* cb = hl[t & 1];
    short* nb = &hl[(t + 1) & 1][0];
    const float (*xr)[4] = xs[t & 1];
    float (*xw)[4] = xs[(t + 1) & 1];

    // ---- k-loop (Wh·h, 32 kt, depth-2 register prefetch) + x-direct act -----
    const short* aptr = cb + arow * LROW + ahalf * 8;
    #pragma unroll
    for (int jt = 0; jt < 2; ++jt) {
      int ntL = wv * 2 + jt;
      const short* bp = wm + (size_t)ntL * (KT_N * 4 * 512) + (lane << 3);
      floatx16 ai = (floatx16)0.0f, af = (floatx16)0.0f,
               ag = (floatx16)0.0f, ao = (floatx16)0.0f;
      short8 b00 = *(const short8*)(bp +    0), b01 = *(const short8*)(bp +  512);
      short8 b02 = *(const short8*)(bp + 1024), b03 = *(const short8*)(bp + 1536);
      short8 b10 = *(const short8*)(bp + 2048), b11 = *(const short8*)(bp + 2560);
      short8 b12 = *(const short8*)(bp + 3072), b13 = *(const short8*)(bp + 3584);
      #pragma unroll 1
      for (int kt = 0; kt < 30; kt += 2) {
        short8 a0 = *(const short8*)(aptr + kt * 16);
        ai = MFMA(a0, b00, ai); af = MFMA(a0, b01, af);
        ag = MFMA(a0, b02, ag); ao = MFMA(a0, b03, ao);
        {   // prefetch kt+2 (kt+2 <= 30, always valid)
          const short* np = bp + (kt + 2) * 2048;
          b00 = *(const short8*)(np);        b01 = *(const short8*)(np + 512);
          b02 = *(const short8*)(np + 1024); b03 = *(const short8*)(np + 1536);
        }
        short8 a1 = *(const short8*)(aptr + kt * 16 + 16);
        ai = MFMA(a1, b10, ai); af = MFMA(a1, b11, af);
        ag = MFMA(a1, b12, ag); ao = MFMA(a1, b13, ao);
        {   // prefetch kt+3 (kt+3 <= 31, always valid)
          const short* np = bp + (kt + 3) * 2048;
          b10 = *(const short8*)(np);        b11 = *(const short8*)(np + 512);
          b12 = *(const short8*)(np + 1024); b13 = *(const short8*)(np + 1536);
        }
      }
      { // tail kt = 30, 31 (held in b0x/b1x)
        short8 a0 = *(const short8*)(aptr + 480);
        ai = MFMA(a0, b00, ai); af = MFMA(a0, b01, af);
        ag = MFMA(a0, b02, ag); ao = MFMA(a0, b03, ao);
        short8 a1 = *(const short8*)(aptr + 496);
        ai = MFMA(a1, b10, ai); af = MFMA(a1, b11, af);
        ag = MFMA(a1, b12, ag); ao = MFMA(a1, b13, ao);
      }
      int col = wv * 64 + jt * 32 + arow;
      #pragma unroll
      for (int r = 0; r < 16; ++r) {
        int row = (r & 3) + ((r >> 2) << 3) + (ahalf << 2);
        float x0 = xr[row][0], x1 = xr[row][1], x2 = xr[row][2], x3 = xr[row][3];
        float gi = ai[r] + wb[jt][0] + wx[jt][0][0]*x0 + wx[jt][0][1]*x1 + wx[jt][0][2]*x2 + wx[jt][0][3]*x3;
        float gf = af[r] + wb[jt][1] + wx[jt][1][0]*x0 + wx[jt][1][1]*x1 + wx[jt][1][2]*x2 + wx[jt][1][3]*x3;
        float gg = ag[r] + wb[jt][2] + wx[jt][2][0]*x0 + wx[jt][2][1]*x1 + wx[jt][2][2]*x2 + wx[jt][2][3]*x3;
        float go = ao[r] + wb[jt][3] + wx[jt][3][0]*x0 + wx[jt][3][1]*x1 + wx[jt][3][2]*x2 + wx[jt][3][3]*x3;
        float cn = sigm(gf) * c_reg[jt][r] + sigm(gi) * tanh_f(gg);
        c_reg[jt][r] = cn;
        nb[row * LROW + col] = (short)f2bf(sigm(go) * tanh_f(cn));
      }
    }
    __syncthreads();                               // B1: h(t+1) complete in nb

    // ---- heads: wave wv handles rows [wv*4, wv*4+4) of nb -------------------
    #pragma unroll 1
    for (int r = 0; r < 4; ++r) {
      int row = wv * 4 + r;
      const short8 hvs = *(const short8*)(nb + row * LROW + lane * 8);
      float hv[8];
      #pragma unroll
      for (int j = 0; j < 8; ++j) hv[j] = bf2f((unsigned short)hvs[j]);
      if (chain == 0) {
        float p0 = 0.f, p1 = 0.f, p2 = 0.f, p3 = 0.f;
        #pragma unroll
        for (int j = 0; j < 8; ++j) {
          p0 += hv[j] * wro[0][j];
          p1 += hv[j] * wro[1][j];
          p2 += hv[j] * wro[2][j];
          p3 += hv[j] * wro[3][j];
        }
        #pragma unroll
        for (int off = 32; off > 0; off >>= 1) {
          p0 += __shfl_xor(p0, off);
          p1 += __shfl_xor(p1, off);
          p2 += __shfl_xor(p2, off);
          p3 += __shfl_xor(p3, off);
        }
        float s0 = fminf(fmaxf(p0 + hb[0], -100.0f), 100.0f);
        float s1 = fminf(fmaxf(p1 + hb[1], -100.0f), 100.0f);
        float s2 = fminf(fmaxf(p2 + hb[2], -100.0f), 100.0f);
        float s3 = fminf(fmaxf(p3 + hb[3], -100.0f), 100.0f);
        if (lane < 4) {
          float v = (lane == 0) ? s0 : (lane == 1) ? s1 : (lane == 2) ? s2 : s3;
          out[(size_t)(r0 + row) * 128 + t * 4 + lane] = v;   // speed_outputs
          xw[row][lane] = v;                                  // ls feedback (f32)
        }
      } else {
        float p0 = 0.f, p1 = 0.f;
        #pragma unroll
        for (int j = 0; j < 8; ++j) {
          p0 += hv[j] * wro[0][j];
          p1 += hv[j] * wro[1][j];
        }
        #pragma unroll
        for (int off = 32; off > 0; off >>= 1) {
          p0 += __shfl_xor(p0, off);
          p1 += __shfl_xor(p1, off);
        }
        float it0 = fmaxf(p0 + hb[0], 0.0f);
        float it1 = fmaxf(p1 + hb[1], 0.0f);
        if (lane < 4) {
          float lp = fmaxf(we[lane * 2] * it0 + we[lane * 2 + 1] * it1 + be[lane], 0.0f);
          xw[row][lane] = lp;                                 // lp feedback (f32)
        }
        if (t == T_DEC - 1 && lane < 2) {
          float m = fmaxf(it0, it1);
          float e0 = __expf(it0 - m), e1 = __expf(it1 - m);
          float v = ((lane == 0) ? e0 : e1) * rcpf(e0 + e1);
          out[(size_t)524288 + (size_t)(r0 + row) * 2 + lane] = v; // crossing
        }
      }
    }
    __syncthreads();                               // B2: x(t+1) complete in xw
  }
}

extern "C" void kernel_launch(void* const* d_in, const int* in_sizes, int n_in,
                              void* d_out, int out_size, void* d_ws, size_t ws_size,
                              hipStream_t stream)
{
  const float* speed    = (const float*)d_in[0];
  const float* pos      = (const float*)d_in[1];
  const float* enc_s_Wi = (const float*)d_in[2];
  const float* enc_s_Wh = (const float*)d_in[3];
  const float* enc_s_b  = (const float*)d_in[4];
  const float* enc_p_Wi = (const float*)d_in[5];
  const float* enc_p_Wh = (const float*)d_in[6];
  const float* enc_p_b  = (const float*)d_in[7];
  const float* dec_s_Wi = (const float*)d_in[8];
  const float* dec_s_Wh = (const float*)d_in[9];
  const float* dec_s_b  = (const float*)d_in[10];
  const float* dec_i_Wi = (const float*)d_in[11];
  const float* dec_i_Wh = (const float*)d_in[12];
  const float* dec_i_b  = (const float*)d_in[13];
  const float* W_fs     = (const float*)d_in[14];
  const float* b_fs     = (const float*)d_in[15];
  const float* W_fc     = (const float*)d_in[16];
  const float* b_fc     = (const float*)d_in[17];
  const float* W_emb    = (const float*)d_in[18];
  const float* b_emb    = (const float*)d_in[19];
  float* out = (float*)d_out;

  char* ws = (char*)d_ws;
  short* wpack = (short*)ws;                 // 4 x 2,162,688 B = 8,650,752 B
  short* h_enc = (short*)(ws + 8650752);     // 2 x 4096 x 512 bf16 = 8,388,608 B
  float* c_enc = (float*)(ws + 17039360);    // 2 x 4096 x 512 f32  = 16,777,216 B

  prep_weights<<<16896, 256, 0, stream>>>(
      enc_s_Wh, enc_s_Wi, enc_s_b,
      enc_p_Wh, enc_p_Wi, enc_p_b,
      dec_s_Wh, dec_s_Wi, dec_s_b,
      dec_i_Wh, dec_i_Wi, dec_i_b,
      wpack);
  lstm_encoder<<<256, 1024, 0, stream>>>(speed, pos, wpack, h_enc, c_enc);
  lstm_decoder<<<256, 512, 0, stream>>>(speed, pos, wpack,
                                        dec_s_Wi, dec_s_b, dec_i_Wi, dec_i_b,
                                        h_enc, c_enc,
                                        W_fs, b_fs, W_fc, b_fc, W_emb, b_emb, out);
}